// Round 2
// baseline (606.985 us; speedup 1.0000x reference)
//
#include <hip/hip_runtime.h>

#define IN_DIM 4096
#define OUT_DIM 4096
#define RANK 16
#define MDIM 8192   // BATCH*SEQ = 4*2048

typedef unsigned short ushort_t;
typedef __attribute__((ext_vector_type(8))) short short8;   // 8 bf16 = 4 VGPRs (MFMA A/B frag)
typedef __attribute__((ext_vector_type(4))) float floatx4;  // MFMA C/D frag
typedef __attribute__((ext_vector_type(4))) ushort_t ushort4_t;

__device__ __forceinline__ ushort_t f2b(float f) {
    union { float f; unsigned int i; } v; v.f = f;
    unsigned int u = v.i;
    u += 0x7FFFu + ((u >> 16) & 1u);   // round-to-nearest-even
    return (ushort_t)(u >> 16);
}

// async global->LDS, 16B per lane. LDS dest is wave-uniform base + lane*16.
#define GLOAD_LDS16(gp, lp)                                                    \
    __builtin_amdgcn_global_load_lds(                                          \
        (__attribute__((address_space(1))) void*)(gp),                         \
        (__attribute__((address_space(3))) void*)(lp), 16, 0, 0)

// ---------------------------------------------------------------------------
// Kernel 0: X fp32 -> bf16. Memory-bound (134 MB read, 67 MB write).
// ---------------------------------------------------------------------------
__global__ __launch_bounds__(256) void convx_kernel(
    const float4* __restrict__ x, ushort4_t* __restrict__ xb, int n4)
{
    int i = blockIdx.x * blockDim.x + threadIdx.x;
    int stride = gridDim.x * blockDim.x;
    for (; i < n4; i += stride) {
        float4 v = x[i];
        ushort4_t o;
        o.x = f2b(v.x); o.y = f2b(v.y); o.z = f2b(v.z); o.w = f2b(v.w);
        xb[i] = o;
    }
}

// ---------------------------------------------------------------------------
// Kernel 1: W_eff[o,i] = org[o,i] + (w1a@w1b)[o,i]*(w2a@w2b)[o,i]*scalar,
// fp32 inputs -> bf16 out. Block covers 64 o-rows x 256 i-cols.
// ---------------------------------------------------------------------------
__global__ __launch_bounds__(256) void weff_kernel(
    const float* __restrict__ orgw,
    const float* __restrict__ w1a, const float* __restrict__ w1b,
    const float* __restrict__ w2a, const float* __restrict__ w2b,
    const float* __restrict__ scalar,
    ushort_t* __restrict__ weff)
{
    __shared__ float s1b[RANK][256];
    __shared__ float s2b[RANK][256];
    __shared__ float s1a[64 * RANK];
    __shared__ float s2a[64 * RANK];

    const int t  = threadIdx.x;
    const int i0 = blockIdx.x * 256;
    const int o0 = blockIdx.y * 64;

    #pragma unroll
    for (int r = 0; r < RANK; ++r) {
        s1b[r][t] = w1b[r * IN_DIM + i0 + t];   // coalesced
        s2b[r][t] = w2b[r * IN_DIM + i0 + t];
    }
    for (int e = t; e < 64 * RANK; e += 256) {
        s1a[e] = w1a[o0 * RANK + e];
        s2a[e] = w2a[o0 * RANK + e];
    }
    __syncthreads();

    const float sc = scalar[0];
    for (int o = 0; o < 64; ++o) {
        float a1 = 0.f, a2 = 0.f;
        #pragma unroll
        for (int r = 0; r < RANK; ++r) {
            a1 += s1a[o * RANK + r] * s1b[r][t];   // s1a broadcast, s1b conflict-free
            a2 += s2a[o * RANK + r] * s2b[r][t];
        }
        const int idx = (o0 + o) * IN_DIM + i0 + t;
        weff[idx] = f2b(orgw[idx] + a1 * a2 * sc);
    }
}

// ---------------------------------------------------------------------------
// Kernel 2: out[m,o] = sum_k Xb[m,k]*W[o,k] + bias[o]  (bf16 in, fp32 out)
// m97-style: 128x128 tile, BK=32, 4 waves each own 64x64 (4x4 MFMA tiles of
// 16x16x32 bf16). global_load_lds width=16 staging, 2-barrier K-loop.
// ---------------------------------------------------------------------------
#define BM 128
#define BN 128
#define BK 32

__global__ __launch_bounds__(256) void gemm_kernel(
    const ushort_t* __restrict__ X,     // [MDIM, IN_DIM] bf16
    const ushort_t* __restrict__ W,     // [OUT_DIM, IN_DIM] bf16 (= W_eff)
    const float* __restrict__ bias,     // [OUT_DIM] fp32
    float* __restrict__ out)            // [MDIM, OUT_DIM] fp32
{
    __shared__ __align__(16) short lA[BM * BK];   // [row][k], row stride 32 bf16 = 64B
    __shared__ __align__(16) short lB[BN * BK];

    const int t    = threadIdx.x;
    const int w    = t >> 6;        // wave 0..3
    const int lane = t & 63;
    const int m0   = blockIdx.y * BM;
    const int n0   = blockIdx.x * BN;

    const int quad  = lane >> 4;    // 0..3
    const int r16   = lane & 15;
    const int mrow0 = (w >> 1) * 64;
    const int ncol0 = (w & 1) * 64;

    // staging: 512 chunks of 16B per tile; wave w covers chunks [w*128, w*128+128)
    const int c0  = w * 128 + lane;
    const int c1  = c0 + 64;
    const int rA0 = c0 >> 2, kA0 = c0 & 3;
    const int rA1 = c1 >> 2, kA1 = c1 & 3;
    const ushort_t* gA0 = X + (size_t)(m0 + rA0) * IN_DIM + kA0 * 8;
    const ushort_t* gA1 = X + (size_t)(m0 + rA1) * IN_DIM + kA1 * 8;
    const ushort_t* gB0 = W + (size_t)(n0 + rA0) * IN_DIM + kA0 * 8;
    const ushort_t* gB1 = W + (size_t)(n0 + rA1) * IN_DIM + kA1 * 8;
    short* lA0 = &lA[(w * 128) * 8];        // wave-uniform LDS bases
    short* lA1 = &lA[(w * 128 + 64) * 8];
    short* lB0 = &lB[(w * 128) * 8];
    short* lB1 = &lB[(w * 128 + 64) * 8];

    // fragment read bases: A[m = mrow0+mi*16+r16][k = quad*8 + j]
    const short* pA = &lA[(mrow0 + r16) * BK + quad * 8];
    const short* pB = &lB[(ncol0 + r16) * BK + quad * 8];

    floatx4 acc[4][4];
    #pragma unroll
    for (int i = 0; i < 4; ++i)
        #pragma unroll
        for (int j = 0; j < 4; ++j)
            acc[i][j] = (floatx4){0.f, 0.f, 0.f, 0.f};

    for (int it = 0; it < IN_DIM / BK; ++it) {
        const int k0 = it * BK;
        __syncthreads();                       // prev-iter LDS reads done
        GLOAD_LDS16(gA0 + k0, lA0);
        GLOAD_LDS16(gA1 + k0, lA1);
        GLOAD_LDS16(gB0 + k0, lB0);
        GLOAD_LDS16(gB1 + k0, lB1);
        __syncthreads();                       // drains vmcnt -> staging visible

        short8 af[4], bfr[4];
        #pragma unroll
        for (int i = 0; i < 4; ++i) {
            af[i]  = *(const short8*)(pA + i * 16 * BK);   // ds_read_b128
            bfr[i] = *(const short8*)(pB + i * 16 * BK);
        }
        #pragma unroll
        for (int mi = 0; mi < 4; ++mi)
            #pragma unroll
            for (int ni = 0; ni < 4; ++ni)
                acc[mi][ni] = __builtin_amdgcn_mfma_f32_16x16x32_bf16(
                    af[mi], bfr[ni], acc[mi][ni], 0, 0, 0);
    }

    // Epilogue. C/D layout: col = lane&15 (n), row = quad*4 + reg (m).
    #pragma unroll
    for (int ni = 0; ni < 4; ++ni) {
        const int gn = n0 + ncol0 + ni * 16 + r16;
        const float bv = bias[gn];
        #pragma unroll
        for (int mi = 0; mi < 4; ++mi) {
            const int gmb = m0 + mrow0 + mi * 16 + quad * 4;
            #pragma unroll
            for (int rr = 0; rr < 4; ++rr) {
                out[(size_t)(gmb + rr) * OUT_DIM + gn] = acc[mi][ni][rr] + bv;
            }
        }
    }
}

extern "C" void kernel_launch(void* const* d_in, const int* in_sizes, int n_in,
                              void* d_out, int out_size, void* d_ws, size_t ws_size,
                              hipStream_t stream) {
    const float* x      = (const float*)d_in[0];  // [4,2048,4096] fp32
    const float* orgw   = (const float*)d_in[1];  // [4096,4096] fp32
    const float* bias   = (const float*)d_in[2];  // [4096] fp32
    const float* w1a    = (const float*)d_in[3];  // [4096,16] fp32
    const float* w1b    = (const float*)d_in[4];  // [16,4096] fp32
    const float* w2a    = (const float*)d_in[5];  // [4096,16] fp32
    const float* w2b    = (const float*)d_in[6];  // [16,4096] fp32
    const float* scalar = (const float*)d_in[7];  // [1] fp32

    // workspace layout: [0, 64MB) X bf16; [64MB, 96MB) W_eff bf16
    ushort_t* xb   = (ushort_t*)d_ws;
    ushort_t* weff = (ushort_t*)d_ws + (size_t)MDIM * IN_DIM;
    float* out = (float*)d_out;

    const int n4 = MDIM * IN_DIM / 4;
    convx_kernel<<<2048, 256, 0, stream>>>((const float4*)x, (ushort4_t*)xb, n4);
    weff_kernel<<<dim3(IN_DIM / 256, OUT_DIM / 64), 256, 0, stream>>>(
        orgw, w1a, w1b, w2a, w2b, scalar, weff);
    gemm_kernel<<<dim3(OUT_DIM / BN, MDIM / BM), 256, 0, stream>>>(
        xb, weff, bias, out);
}